// Round 11
// baseline (10211.082 us; speedup 1.0000x reference)
//
#include <hip/hip_runtime.h>
#include <math.h>

// Round 13: weights out of LDS -> 4 independent full-batch waves per SIMD.
//  - r7..r12 all land ~6800 scan: per-wave stalls ~65% unfilled at 2
//    waves/SIMD. Every prior TLP test was confounded (r6: 64 VGPR+refetch;
//    r9: one lgkmcnt queue; r10b: spill; r11b: team flag coupling).
//  - r13: weights read straight from global (L2/L3-resident, ~640B/layer/wave
//    of batched predictable loads); LDS keeps only per-wave scratch (4KB) +
//    bias (6.5KB) = 22.9KB/block. Block = 256 thr = 4 INDEPENDENT batches,
//    grid 512 -> 2-4 blocks/CU; VGPR ~124 -> 4 waves/SIMD, zero coupling.
//  - Compute body identical to r12 (in-register token mixing via x16 MFMA
//    identity; channel mixing with 2 scratch round-trips).
//
// Fragment layouts (gfx950, verified r2-r12):
//   x32: A[m=lane&15][k=8q+j], B[k=8q+j][n=lane&15]
//   x16: A[m=lane&15][k=4q+j], B[k=4q+j][n=lane&15]
//   C (both): col=lane&15, row=4q+reg.

namespace {
constexpr int Tt = 256, NL = 3;

typedef float    f32x4 __attribute__((ext_vector_type(4)));
typedef _Float16 half2 __attribute__((ext_vector_type(2)));
typedef _Float16 h16x4 __attribute__((ext_vector_type(4)));
typedef _Float16 h16x8 __attribute__((ext_vector_type(8)));

#define MFMA32(a, b, c) __builtin_amdgcn_mfma_f32_16x16x32_f16((a), (b), (c), 0, 0, 0)
#define MFMA16(a, b, c) __builtin_amdgcn_mfma_f32_16x16x16f16((a), (b), (c), 0, 0, 0)

__device__ __forceinline__ half2 h2c(float v) { return (half2)((_Float16)v); }
__device__ __forceinline__ f32x4 f4s(float v) { return (f32x4)v; }
__device__ __forceinline__ half2 pkrtz(float a, float b) {
    return __builtin_bit_cast(half2, __builtin_amdgcn_cvt_pkrtz(a, b));
}
__device__ __forceinline__ void st4h(short* p, half2 a, half2 b) {
    uint2 v;
    v.x = __builtin_bit_cast(unsigned int, a);
    v.y = __builtin_bit_cast(unsigned int, b);
    *(uint2*)p = v;
}
__device__ __forceinline__ h16x4 h4(half2 a, half2 b) {
    h16x4 v; v[0] = a[0]; v[1] = a[1]; v[2] = b[0]; v[3] = b[1]; return v;
}
// packed f16 GELU, no transcendentals (unchanged numerics from r5-r12)
__device__ __forceinline__ half2 gelu_pk(half2 x) {
    half2 tc = __builtin_elementwise_min(__builtin_elementwise_max(x, h2c(-3.0f)), h2c(3.0f));
    half2 s = (tc * tc) * h2c(0.125f);
    half2 p = s * h2c(0.1455169f) + h2c(-0.446340f);
    p = s * p + h2c(0.604927f);
    p = s * p + h2c(-0.529702f);
    p = s * p + h2c(0.3989423f);
    return x * (h2c(0.5f) + tc * p);
}
__device__ __forceinline__ float gelu_f(float x) {
    float tc = fminf(fmaxf(x, -3.f), 3.f);
    float s = tc * tc;
    float p = fmaf(s, 3.55266e-5f, -8.71758e-4f);
    p = fmaf(s, p, 9.45198e-3f);
    p = fmaf(s, p, -6.62128e-2f);
    p = fmaf(s, p, 0.3989423f);
    return x * fmaf(tc, p, 0.5f);
}
// sum across the 16-lane DPP row (all lanes get the total)
__device__ __forceinline__ float rowsum16(float x) {
    x += __builtin_bit_cast(float, __builtin_amdgcn_update_dpp(0, __builtin_bit_cast(int, x), 0x121, 0xf, 0xf, false));
    x += __builtin_bit_cast(float, __builtin_amdgcn_update_dpp(0, __builtin_bit_cast(int, x), 0x122, 0xf, 0xf, false));
    x += __builtin_bit_cast(float, __builtin_amdgcn_update_dpp(0, __builtin_bit_cast(int, x), 0x124, 0xf, 0xf, false));
    x += __builtin_bit_cast(float, __builtin_amdgcn_update_dpp(0, __builtin_bit_cast(int, x), 0x128, 0xf, 0xf, false));
    return x;
}
__device__ __forceinline__ short f2h(float x) {
    return __builtin_bit_cast(short, (_Float16)x);
}

// ws layout (shorts/f16) — identical to r12's prep:
//   A1 x16 frags [0,6144): tiles ((il*4+u)*2+kc)*256, elem lane*4+j
//       = tiW[il][ld=16kc+4q+j][th=16u+c]
//   A2 x16 frags [6144,12288): tiles ((il*2+mt)*4+kc)*256
//       = toW[il][th=16kc+4q+j][ld=16mt+c]
//   A3 x32 frags [12288,36864): ciW (as r5-r9)
//   B4 x32 frags [36864,61440): coW (as r5-r9)
//   W2F fp32 tail kept for layout (unused by scan)
__global__ void lno_prep(const float* __restrict__ tiW, const float* __restrict__ toW,
                         const float* __restrict__ ciW, const float* __restrict__ coW,
                         const float* __restrict__ physW2, short* __restrict__ wsf) {
    int id = blockIdx.x * 256 + threadIdx.x;  // 0..65535
    if (id < 6144) {            // A1 x16: m=th, k=ld-chunk
        int e = id & 255, tile = id >> 8;           // 24 tiles
        int lane = e >> 2, j = e & 3;
        int q = lane >> 4, cc = lane & 15;
        int kc = tile & 1, u = (tile >> 1) & 3, il = tile >> 3;
        wsf[id] = f2h(tiW[il * 2048 + (16 * kc + 4 * q + j) * 64 + 16 * u + cc]);
    } else if (id < 12288) {    // A2 x16: m=ld-half, k=th-chunk
        int t = id - 6144;
        int e = t & 255, tile = t >> 8;             // 24 tiles
        int lane = e >> 2, j = e & 3;
        int q = lane >> 4, cc = lane & 15;
        int kc = tile & 3, mt = (tile >> 2) & 1, il = tile >> 3;
        wsf[id] = f2h(toW[il * 2048 + (16 * kc + 4 * q + j) * 32 + 16 * mt + cc]);
    } else if (id < 36864) {    // A3 x32: m=ch, k=w
        int t = id - 12288;
        int j = t & 7, lane = (t >> 3) & 63, g = t >> 9;
        int il = g >> 4, mtc = (g >> 1) & 7, ks = g & 1;
        int m = mtc * 16 + (lane & 15), k = ks * 32 + (lane >> 4) * 8 + j;
        wsf[id] = f2h(ciW[il * 8192 + k * 128 + m]);
    } else if (id < 61440) {    // B4 x32: k=ch, n=w
        int t = id - 36864;
        int j = t & 7, lane = (t >> 3) & 63, g = t >> 9;
        int il = g >> 4, nt = (g >> 2) & 3, ks = g & 3;
        int n = nt * 16 + (lane & 15), k = ks * 32 + (lane >> 4) * 8 + j;
        wsf[id] = f2h(coW[il * 8192 + k * 64 + n]);
    } else if (id < 65536) {
        int t = id - 61440;
        int w = t >> 6, k = t & 63;
        ((float*)(wsf + 61440))[t] = physW2[k * 64 + w];
    }
}

// phys MLP pre-pass (unchanged): p stored f16 in d_out's [b,t] 128B slot,
// permuted so scan lane (q,c) reads its 4 values {w=nt*16+c} as one 8B load.
__global__ void lno_phys(const float* __restrict__ phys, const float* __restrict__ physW1,
                         const float* __restrict__ physb1, const float* __restrict__ physW2,
                         const float* __restrict__ physb2, short* __restrict__ pout) {
    __shared__ float hsh[4][64];
    const int lane = threadIdx.x & 63, wv = threadIdx.x >> 6;
    const size_t bt = (size_t)blockIdx.x * 4 + wv;
    const float* pt = phys + bt * 8;
    float4 px0 = *(const float4*)pt, px1 = *(const float4*)(pt + 4);
    float a = physb1[lane];
    a = fmaf(px0.x, physW1[0 * 64 + lane], a);
    a = fmaf(px0.y, physW1[1 * 64 + lane], a);
    a = fmaf(px0.z, physW1[2 * 64 + lane], a);
    a = fmaf(px0.w, physW1[3 * 64 + lane], a);
    a = fmaf(px1.x, physW1[4 * 64 + lane], a);
    a = fmaf(px1.y, physW1[5 * 64 + lane], a);
    a = fmaf(px1.z, physW1[6 * 64 + lane], a);
    a = fmaf(px1.w, physW1[7 * 64 + lane], a);
    hsh[wv][lane] = gelu_f(a);
    float acc = physb2[lane];
#pragma unroll
    for (int k = 0; k < 64; ++k) acc = fmaf(hsh[wv][k], physW2[k * 64 + lane], acc);
    pout[bt * 64 + (lane & 15) * 4 + (lane >> 4)] = f2h(acc);
}

// block = 256 thr = 4 waves = 4 INDEPENDENT batches; grid 512 -> 2-4 blocks/CU
// (VGPR-limited). Weights read from global (L2-resident); LDS = per-wave
// scratch + bias only. No barriers in the t loop. pbuf/out alias d_out
// (read-before-write per wave, as r7-r12).
__global__ __launch_bounds__(256, 2) void lno_scan(
    const float* __restrict__ latents, const float* __restrict__ pos_emb,
    const float* __restrict__ tokW,    const float* __restrict__ tokb,
    const float* __restrict__ tn_g,    const float* __restrict__ tn_b,
    const float* __restrict__ tib,     const float* __restrict__ tob,
    const float* __restrict__ cn_g,    const float* __restrict__ cn_b,
    const float* __restrict__ cib,     const float* __restrict__ cob,
    const float* __restrict__ hn_g,    const float* __restrict__ hn_b,
    const float* __restrict__ headW,   const float* __restrict__ headb,
    const short* __restrict__ wsf,     const short* pbuf, float* out)
{
    __shared__ __align__(16) short scr[4][2048];  // per-wave channel-mix scratch (4KB)
    __shared__ __align__(16) float biasL[1632];   // tib[0) tob[192) cib[288) tn_g[672)
                                                  // tn_b[864) cn_g[1056) cn_b[1248) cob[1440)

    const int tid = threadIdx.x, lane = tid & 63, wv = tid >> 6;
    const int q = lane >> 4, c = lane & 15;
    const int b = blockIdx.x * 4 + wv;
    short* sc = scr[wv];

    const short* A1G = wsf;            // global (L2-resident) weight frags
    const short* A2G = wsf + 6144;
    const short* A3G = wsf + 12288;
    const short* B4G = wsf + 36864;

    // ---- one-shot bias/LN-param stage ----
    for (int i = tid; i < 192; i += 256) {
        biasL[i] = tib[i];
        biasL[672 + i]  = tn_g[i];
        biasL[864 + i]  = tn_b[i];
        biasL[1056 + i] = cn_g[i];
        biasL[1248 + i] = cn_b[i];
        biasL[1440 + i] = cob[i];
    }
    for (int i = tid; i < 96;  i += 256) biasL[192 + i] = tob[i];
    for (int i = tid; i < 384; i += 256) biasL[288 + i] = cib[i];

    // ---- hoisted per-lane constants ----
    float tokw_r[4], gh_r[4];
#pragma unroll
    for (int nt = 0; nt < 4; ++nt) {
        tokw_r[nt] = tokW[nt * 16 + c];
        gh_r[nt]   = hn_g[nt * 16 + c] * headW[nt * 16 + c];
    }
    float bhp = 0.f;
#pragma unroll
    for (int nt = 0; nt < 4; ++nt) bhp = fmaf(hn_b[nt * 16 + c], headW[nt * 16 + c], bhp);
    const float bh = rowsum16(bhp) + headb[0];

    // pos_emb+tokb pre-sum, f16-packed: peh[mt][r][nt-packed] (16 VGPR)
    h16x4 peh[2][4];
#pragma unroll
    for (int mt = 0; mt < 2; ++mt)
#pragma unroll
        for (int r = 0; r < 4; ++r) {
            const int row = mt * 16 + q * 4 + r;
            float v0 = pos_emb[row * 64 +  0 + c] + tokb[ 0 + c];
            float v1 = pos_emb[row * 64 + 16 + c] + tokb[16 + c];
            float v2 = pos_emb[row * 64 + 32 + c] + tokb[32 + c];
            float v3 = pos_emb[row * 64 + 48 + c] + tokb[48 + c];
            peh[mt][r] = h4(pkrtz(v0, v1), pkrtz(v2, v3));
        }

    f32x4 cur8[2];
#pragma unroll
    for (int mt = 0; mt < 2; ++mt)
        cur8[mt] = *(const f32x4*)(latents + b * 32 + mt * 16 + q * 4);

    f32x4 tok[2][4];

    __syncthreads();  // biasL ready; last barrier.

    auto stats = [&](f32x4 (&mean)[2], f32x4 (&rsig)[2]) {
#pragma unroll
        for (int mt = 0; mt < 2; ++mt) {
            f32x4 s4 = (tok[mt][0] + tok[mt][1]) + (tok[mt][2] + tok[mt][3]);
            f32x4 q4 = tok[mt][0] * tok[mt][0];
            q4 = __builtin_elementwise_fma(tok[mt][1], tok[mt][1], q4);
            q4 = __builtin_elementwise_fma(tok[mt][2], tok[mt][2], q4);
            q4 = __builtin_elementwise_fma(tok[mt][3], tok[mt][3], q4);
#pragma unroll
            for (int r = 0; r < 4; ++r) {
                float ss = rowsum16(s4[r]);
                float qq = rowsum16(q4[r]);
                float m = ss * 0.015625f;
                float v = fmaf(-m, m, qq * 0.015625f);
                mean[mt][r] = m;
                rsig[mt][r] = __builtin_amdgcn_rsqf(v + 1e-5f);
            }
        }
    };

    const short* pb = pbuf + (size_t)b * Tt * 64 + c * 4;
    h16x4 pvc = *(const h16x4*)pb;

#pragma unroll 1
    for (int t = 0; t < Tt; ++t) {
        const h16x4 pv = pvc;
        if (t + 1 < Tt) pvc = *(const h16x4*)(pb + (t + 1) * 64);

        // ======== token init from f16 peh + pv ========
        {
            f32x4 pvx;
#pragma unroll
            for (int nt = 0; nt < 4; ++nt) pvx[nt] = (float)pv[nt];
#pragma unroll
            for (int mt = 0; mt < 2; ++mt)
#pragma unroll
                for (int r = 0; r < 4; ++r) {
#pragma unroll
                    for (int nt = 0; nt < 4; ++nt)
                        tok[mt][nt][r] = fmaf(cur8[mt][r], tokw_r[nt],
                                              (float)peh[mt][r][nt] + pvx[nt]);
                }
        }

#pragma unroll
        for (int il = 0; il < NL; ++il) {
            // ======== token mixing (in-register, x16 MFMA) ========
            f32x4 mean[2], rsig[2];
            stats(mean, rsig);
            // LN1 -> y x16 B-frags in regs (yh[mt][nt], j==r)
            h16x4 yh[2][4];
#pragma unroll
            for (int nt = 0; nt < 4; ++nt) {
                const float tng = biasL[672 + il * 64 + nt * 16 + c];
                const float tnb = biasL[864 + il * 64 + nt * 16 + c];
#pragma unroll
                for (int mt = 0; mt < 2; ++mt) {
                    f32x4 y = __builtin_elementwise_fma((tok[mt][nt] - mean[mt]) * rsig[mt],
                                                        f4s(tng), f4s(tnb));
                    yh[mt][nt] = h4(pkrtz(y[0], y[1]), pkrtz(y[2], y[3]));
                }
            }
            // tob pre-add (per-row); mm2 then accumulates in place
#pragma unroll
            for (int mt = 0; mt < 2; ++mt) {
                const f32x4 tb = *(const f32x4*)&biasL[192 + il * 32 + mt * 16 + q * 4];
#pragma unroll
                for (int nt = 0; nt < 4; ++nt) tok[mt][nt] += tb;
            }
            // mm1: h = gelu(tiW^T y + tib); output C-pieces ARE mm2's B-frags
            h16x4 b2[4][4];
#pragma unroll
            for (int u = 0; u < 4; ++u) {
                const h16x4 a1k0 = *(const h16x4*)(A1G + ((il * 4 + u) * 2 + 0) * 256 + lane * 4);
                const h16x4 a1k1 = *(const h16x4*)(A1G + ((il * 4 + u) * 2 + 1) * 256 + lane * 4);
                const f32x4 bi = *(const f32x4*)&biasL[il * 64 + u * 16 + q * 4];
#pragma unroll
                for (int nt = 0; nt < 4; ++nt) {
                    f32x4 hv = MFMA16(a1k0, yh[0][nt], bi);
                    hv = MFMA16(a1k1, yh[1][nt], hv);
                    b2[u][nt] = h4(gelu_pk(pkrtz(hv[0], hv[1])),
                                   gelu_pk(pkrtz(hv[2], hv[3])));
                }
            }
            // mm2: tok += toW^T h, operands in regs + global weight frags
#pragma unroll
            for (int mt = 0; mt < 2; ++mt)
#pragma unroll
                for (int kc = 0; kc < 4; ++kc) {
                    const h16x4 a2 = *(const h16x4*)(A2G + ((il * 2 + mt) * 4 + kc) * 256 + lane * 4);
#pragma unroll
                    for (int nt = 0; nt < 4; ++nt)
                        tok[mt][nt] = MFMA16(a2, b2[kc][nt], tok[mt][nt]);
                }

            // ======== channel mixing (r12-verbatim; transposes inherent) ========
            stats(mean, rsig);
            float cng[4], cnb[4];
#pragma unroll
            for (int nt = 0; nt < 4; ++nt) {
                cng[nt] = biasL[1056 + il * 64 + nt * 16 + c];
                cnb[nt] = biasL[1248 + il * 64 + nt * 16 + c];
            }
            // LN2 -> sc (B3 frags, swizzled slots), packed apply + scalar b16 scatter
#pragma unroll
            for (int mt = 0; mt < 2; ++mt)
#pragma unroll
                for (int nt = 0; nt < 4; ++nt) {
                    f32x4 v4 = __builtin_elementwise_fma((tok[mt][nt] - mean[mt]) * rsig[mt],
                                                         f4s(cng[nt]), f4s(cnb[nt]));
#pragma unroll
                    for (int r = 0; r < 4; ++r)
                        sc[(mt * 2 + (nt >> 1)) * 512 +
                           (q * 2 + (c >> 3) + 16 * r + 8 * (nt & 1)) * 8 + (c & 7)] = f2h(v4[r]);
                }
            h16x8 b3[4];
            {
                const int lp = ((c >> 2) * 2 + (q & 1)) + 8 * ((c & 3) * 2 + (q >> 1));
#pragma unroll
                for (int F = 0; F < 4; ++F) b3[F] = *(const h16x8*)&sc[F * 512 + lp * 8];
            }
            // pre-add cob (per-col); mm4 accumulates in place
#pragma unroll
            for (int nt = 0; nt < 4; ++nt) {
                const f32x4 cv = f4s(biasL[1440 + il * 64 + nt * 16 + c]);
#pragma unroll
                for (int mt = 0; mt < 2; ++mt) tok[mt][nt] += cv;
            }
            // mm3 (gelu -> sc) + mm4, by ch-half hh
#pragma unroll
            for (int hh = 0; hh < 2; ++hh) {
#pragma unroll
                for (int mm = 0; mm < 4; ++mm) {
                    const int mtc = hh * 4 + mm;
                    const h16x8 a30 = *(const h16x8*)(A3G + il * 8192 + (mtc * 2 + 0) * 512 + lane * 8);
                    const h16x8 a31 = *(const h16x8*)(A3G + il * 8192 + (mtc * 2 + 1) * 512 + lane * 8);
                    const f32x4 bi3 = *(const f32x4*)&biasL[288 + il * 128 + mtc * 16 + q * 4];
#pragma unroll
                    for (int ntl = 0; ntl < 2; ++ntl) {
                        f32x4 acc = MFMA32(a30, b3[ntl * 2 + 0], bi3);
                        acc = MFMA32(a31, b3[ntl * 2 + 1], acc);
                        st4h(&sc[((ntl * 2 + ((mtc >> 1) & 1)) * 64 +
                                  ((mtc & 1) * 2 + (q >> 1)) * 16 + c) * 8 + (q & 1) * 4],
                             gelu_pk(pkrtz(acc[0], acc[1])), gelu_pk(pkrtz(acc[2], acc[3])));
                    }
                }
                h16x8 a4[2][2];
#pragma unroll
                for (int mt = 0; mt < 2; ++mt)
#pragma unroll
                    for (int kk = 0; kk < 2; ++kk)
                        a4[mt][kk] = *(const h16x8*)&sc[((mt * 2 + kk) * 64 + lane) * 8];
#pragma unroll
                for (int nt = 0; nt < 4; ++nt) {
                    const h16x8 b40 = *(const h16x8*)(B4G + il * 8192 + (nt * 4 + hh * 2 + 0) * 512 + lane * 8);
                    const h16x8 b41 = *(const h16x8*)(B4G + il * 8192 + (nt * 4 + hh * 2 + 1) * 512 + lane * 8);
#pragma unroll
                    for (int mt = 0; mt < 2; ++mt) {
                        tok[mt][nt] = MFMA32(a4[mt][0], b40, tok[mt][nt]);
                        tok[mt][nt] = MFMA32(a4[mt][1], b41, tok[mt][nt]);
                    }
                }
            }
        }  // il

        // ======== head ========
        {
            f32x4 mean[2], rsig[2];
            stats(mean, rsig);
#pragma unroll
            for (int mt = 0; mt < 2; ++mt) {
                f32x4 l4 = (tok[mt][0] - mean[mt]) * f4s(gh_r[0]);
                l4 = __builtin_elementwise_fma(tok[mt][1] - mean[mt], f4s(gh_r[1]), l4);
                l4 = __builtin_elementwise_fma(tok[mt][2] - mean[mt], f4s(gh_r[2]), l4);
                l4 = __builtin_elementwise_fma(tok[mt][3] - mean[mt], f4s(gh_r[3]), l4);
                f32x4 ls;
#pragma unroll
                for (int r = 0; r < 4; ++r) ls[r] = rowsum16(l4[r]);
                f32x4 nv = cur8[mt] + __builtin_elementwise_fma(rsig[mt], ls, f4s(bh));
                nv = __builtin_elementwise_min(__builtin_elementwise_max(nv, f4s(0.f)), f4s(1.f));
                cur8[mt] = nv;
            }
            if (c == 0) {
                float* op = out + ((size_t)b * Tt + t) * 32 + q * 4;
                *(f32x4*)(op) = cur8[0];
                *(f32x4*)(op + 16) = cur8[1];
            }
        }
    }  // t
}
}  // namespace

extern "C" void kernel_launch(void* const* d_in, const int* in_sizes, int n_in,
                              void* d_out, int out_size, void* d_ws, size_t ws_size,
                              hipStream_t stream) {
    (void)in_sizes; (void)n_in; (void)ws_size; (void)out_size;
    const float* phys    = (const float*)d_in[0];
    const float* latents = (const float*)d_in[1];
    const float* pos_emb = (const float*)d_in[2];
    const float* tokW    = (const float*)d_in[3];
    const float* tokb    = (const float*)d_in[4];
    const float* physW1  = (const float*)d_in[5];
    const float* physb1  = (const float*)d_in[6];
    const float* physW2  = (const float*)d_in[7];
    const float* physb2  = (const float*)d_in[8];
    const float* tn_g    = (const float*)d_in[9];
    const float* tn_b    = (const float*)d_in[10];
    const float* tiW     = (const float*)d_in[11];
    const float* tib     = (const float*)d_in[12];
    const float* toW     = (const float*)d_in[13];
    const float* tob     = (const float*)d_in[14];
    const float* cn_g    = (const float*)d_in[15];
    const float* cn_b    = (const float*)d_in[16];
    const float* ciW     = (const float*)d_in[17];
    const float* cib     = (const float*)d_in[18];
    const float* coW     = (const float*)d_in[19];
    const float* cob     = (const float*)d_in[20];
    const float* hn_g    = (const float*)d_in[21];
    const float* hn_b    = (const float*)d_in[22];
    const float* headW   = (const float*)d_in[23];
    const float* headb   = (const float*)d_in[24];

    lno_prep<<<dim3(256), dim3(256), 0, stream>>>(tiW, toW, ciW, coW, physW2, (short*)d_ws);
    lno_phys<<<dim3(131072), dim3(256), 0, stream>>>(phys, physW1, physb1, physW2, physb2,
                                                     (short*)d_out);
    // scan: 512 blocks (2-4/CU), 4 waves/block = 4 independent batches
    lno_scan<<<dim3(512), dim3(256), 0, stream>>>(
        latents, pos_emb, tokW, tokb, tn_g, tn_b, tib, tob,
        cn_g, cn_b, cib, cob, hn_g, hn_b, headW, headb,
        (const short*)d_ws, (const short*)d_out, (float*)d_out);
}